// Round 8
// baseline (1466.439 us; speedup 1.0000x reference)
//
#include <hip/hip_runtime.h>
#include <cstdint>
#include <cstddef>

// Problem constants
#define T_SEQ 512
#define BATCH 128
#define HID   128
#define G4    512      // 4*H
#define NCLS  10

typedef unsigned short u16;
typedef unsigned int   u32;
typedef short bf16x8 __attribute__((ext_vector_type(8)));   // 8 bf16 = 4 VGPR
typedef float f32x4  __attribute__((ext_vector_type(4)));   // MFMA acc

__device__ __forceinline__ float sigmoidf_(float x) {
    return 1.f / (1.f + __expf(-x));
}
__device__ __forceinline__ float tanhf_(float x) {
    return 2.f / (1.f + __expf(-2.f * x)) - 1.f;
}

__device__ __forceinline__ u16 bf16rne(float f) {
    u32 u = __float_as_uint(f);
    u32 r = (u + 0x7fffu + ((u >> 16) & 1u)) >> 16;
    return (u16)r;
}
__device__ __forceinline__ float bf16tof(u16 s) {
    return __uint_as_float(((u32)s) << 16);
}
__device__ __forceinline__ uint4 pack8(const u16* h) {
    uint4 u;
    u.x = (u32)h[0] | ((u32)h[1] << 16);
    u.y = (u32)h[2] | ((u32)h[3] << 16);
    u.z = (u32)h[4] | ((u32)h[5] << 16);
    u.w = (u32)h[6] | ((u32)h[7] << 16);
    return u;
}

// ---------------------------------------------------------------------------
// prep_w: split the three input-projection weight matrices into bf16 hi/lo
// pairs with K zero-padded (300 -> 320 for layer 0). Runs once per launch.
// ---------------------------------------------------------------------------
__global__ __launch_bounds__(256)
void prep_w(const float* __restrict__ w0f, const float* __restrict__ w0r,
            const float* __restrict__ w1f,
            u16* __restrict__ W0f1, u16* __restrict__ W0f2,
            u16* __restrict__ W0r1, u16* __restrict__ W0r2,
            u16* __restrict__ W1f1, u16* __restrict__ W1f2)
{
    int idx = blockIdx.x * 256 + threadIdx.x;
    if (idx < 512 * 320) {
        int r = idx / 320, k = idx - r * 320;
        float v = (k < 300) ? w0f[r * 300 + k] : 0.f;
        u16 a = bf16rne(v);
        W0f1[idx] = a; W0f2[idx] = bf16rne(v - bf16tof(a));
        v = (k < 300) ? w0r[r * 300 + k] : 0.f;
        a = bf16rne(v);
        W0r1[idx] = a; W0r2[idx] = bf16rne(v - bf16tof(a));
    }
    if (idx < 512 * 256) {
        float v = w1f[idx];
        u16 a = bf16rne(v);
        W1f1[idx] = a; W1f2[idx] = bf16rne(v - bf16tof(a));
    }
}

// ---------------------------------------------------------------------------
// Split-bf16 MFMA GEMM (unchanged from round 7; passed at absmax 7.6e-6).
// C = A1*W1 + A1*W2 + A2*W1; A split on the fly in the staging path.
// ---------------------------------------------------------------------------
__global__ __launch_bounds__(256)
void gemm_mfma(const float* __restrict__ A, const int* __restrict__ rows,
               int lda, int Kp,
               const u16* __restrict__ W1, const u16* __restrict__ W2,
               const float* __restrict__ bih, const float* __restrict__ bhh,
               float* __restrict__ out, int tcshift, int tc0)
{
    __shared__ __align__(16) u16 lA1[128][40];
    __shared__ __align__(16) u16 lA2[128][40];
    __shared__ __align__(16) u16 lW1[128][40];
    __shared__ __align__(16) u16 lW2[128][40];

    const int tid = threadIdx.x;
    const int tn = blockIdx.x & 3;
    const int tm = blockIdx.x >> 2;
    const int m0 = tm * 128, n0 = tn * 128;

    const int wave = tid >> 6, lane = tid & 63;
    const int wm = wave & 1, wn = wave >> 1;
    const int quad = lane >> 4, l16 = lane & 15;

    const int srow = tid >> 1;
    const int sk   = (tid & 1) * 16;

    const float* arow;
    {
        int m  = m0 + srow;
        int b  = m >> tcshift;
        int tt = m & ((1 << tcshift) - 1);
        int grow = b * T_SEQ + tc0 + tt;
        int r = rows ? rows[grow] : grow;
        arow = A + (size_t)r * lda;
    }
    const u16* w1row = W1 + (size_t)(n0 + srow) * Kp + sk;
    const u16* w2row = W2 + (size_t)(n0 + srow) * Kp + sk;

    f32x4 acc[4][4];
#pragma unroll
    for (int i = 0; i < 4; i++)
#pragma unroll
        for (int j = 0; j < 4; j++) acc[i][j] = f32x4{0.f, 0.f, 0.f, 0.f};

    for (int k0 = 0; k0 < Kp; k0 += 32) {
        float av[16];
#pragma unroll
        for (int v = 0; v < 4; v++) {
            int k = k0 + sk + v * 4;
            float4 t = {0.f, 0.f, 0.f, 0.f};
            if (k + 4 <= lda) t = *(const float4*)(arow + k);
            av[v * 4 + 0] = t.x; av[v * 4 + 1] = t.y;
            av[v * 4 + 2] = t.z; av[v * 4 + 3] = t.w;
        }
        uint4 wv1a = *(const uint4*)(w1row + k0);
        uint4 wv1b = *(const uint4*)(w1row + k0 + 8);
        uint4 wv2a = *(const uint4*)(w2row + k0);
        uint4 wv2b = *(const uint4*)(w2row + k0 + 8);

        u16 h1[16], h2[16];
#pragma unroll
        for (int j = 0; j < 16; j++) {
            u16 a = bf16rne(av[j]);
            h1[j] = a;
            h2[j] = bf16rne(av[j] - bf16tof(a));
        }

        __syncthreads();
        *(uint4*)&lA1[srow][sk]     = pack8(h1);
        *(uint4*)&lA1[srow][sk + 8] = pack8(h1 + 8);
        *(uint4*)&lA2[srow][sk]     = pack8(h2);
        *(uint4*)&lA2[srow][sk + 8] = pack8(h2 + 8);
        *(uint4*)&lW1[srow][sk]     = wv1a;
        *(uint4*)&lW1[srow][sk + 8] = wv1b;
        *(uint4*)&lW2[srow][sk]     = wv2a;
        *(uint4*)&lW2[srow][sk + 8] = wv2b;
        __syncthreads();

        bf16x8 fa1[4], fa2[4], fw1[4], fw2[4];
#pragma unroll
        for (int t = 0; t < 4; t++) {
            int ar = wm * 64 + t * 16 + l16;
            int wr = wn * 64 + t * 16 + l16;
            fa1[t] = *(const bf16x8*)&lA1[ar][quad * 8];
            fa2[t] = *(const bf16x8*)&lA2[ar][quad * 8];
            fw1[t] = *(const bf16x8*)&lW1[wr][quad * 8];
            fw2[t] = *(const bf16x8*)&lW2[wr][quad * 8];
        }

#pragma unroll
        for (int mt = 0; mt < 4; mt++)
#pragma unroll
            for (int nt = 0; nt < 4; nt++)
                acc[mt][nt] = __builtin_amdgcn_mfma_f32_16x16x32_bf16(
                    fa1[mt], fw1[nt], acc[mt][nt], 0, 0, 0);
#pragma unroll
        for (int mt = 0; mt < 4; mt++)
#pragma unroll
            for (int nt = 0; nt < 4; nt++)
                acc[mt][nt] = __builtin_amdgcn_mfma_f32_16x16x32_bf16(
                    fa1[mt], fw2[nt], acc[mt][nt], 0, 0, 0);
#pragma unroll
        for (int mt = 0; mt < 4; mt++)
#pragma unroll
            for (int nt = 0; nt < 4; nt++)
                acc[mt][nt] = __builtin_amdgcn_mfma_f32_16x16x32_bf16(
                    fa2[mt], fw1[nt], acc[mt][nt], 0, 0, 0);
    }

#pragma unroll
    for (int nt = 0; nt < 4; nt++) {
        int n = n0 + wn * 64 + nt * 16 + l16;
        float bv = bih[n] + bhh[n];
#pragma unroll
        for (int mt = 0; mt < 4; mt++) {
            int mb = m0 + wm * 64 + mt * 16 + quad * 4;
#pragma unroll
            for (int r = 0; r < 4; r++)
                out[(size_t)(mb + r) * G4 + n] = acc[mt][nt][r] + bv;
        }
    }
}

// ---------------------------------------------------------------------------
// LSTM recurrence, 1024-thread 8-way split-K octet layout.
//
// ROUND 5/7 MODEL: cost = threads x h-bytes/thread (LDS instr issue) plus
// spilled-weight re-stream (128-float arrays never stay resident: VGPR=84).
// FIX: thread j -> octet o=j>>3 = unit u, kq=j&7 = k-chunk. Thread holds the
// 4 gate rows of unit u over k in [16kq,16kq+16) = 64 weight VGPRs (+~40
// working < the hard 128-VGPR cap of a 1024-thread WG -> register-resident).
// Per step: 4 ds_read_b128 (vs 32; kq<->kq+2 is 2-way bank aliasing = free,
// kq+4 same-address broadcast), 64 FMA, butterfly transpose-reduce (xor
// 4/2/1) -> thread kq holds gate kq&3 of unit u, width-8 shuffles combine
// i/f/g/o, c replicated in-octet, h double-buffered -> ONE barrier/step.
// All fp32 (round-6 lesson: weight quantization biases accumulate coherently).
// MODE 0: fused l0 fwd+rev (grid 256; dir=wg>>7), writes h0cat.
// MODE 1: single forward dir (grid 128), state only.
// ---------------------------------------------------------------------------
template <int MODE>
__global__ __launch_bounds__(1024)
void lstm_rec(const float* __restrict__ xg0, const float* __restrict__ xg1,
              const float* __restrict__ whh_f, const float* __restrict__ whh_r,
              float* __restrict__ hout,
              float* __restrict__ hst_f, float* __restrict__ cst_f,
              float* __restrict__ hst_r, float* __restrict__ cst_r,
              int Tc, int tc0f, int tc0r, int first)
{
    const int wg  = blockIdx.x;
    const int dir = (MODE == 0) ? (wg >> 7) : 0;
    const int b   = wg & 127;
    const float* xgb = (dir ? xg1 : xg0) + (size_t)b * Tc * G4;
    const float* whh = dir ? whh_r : whh_f;
    float* hst = dir ? hst_r : hst_f;
    float* cst = dir ? cst_r : cst_f;
    const int tc0 = dir ? tc0r : tc0f;

    const int j  = threadIdx.x;   // 0..1023
    const int u  = j >> 3;        // hidden unit (octet)
    const int kq = j & 7;         // k-chunk index
    const int gf = kq & 3;        // gate this thread finalizes: 0=i 1=f 2=g 3=o
    const int row = gf * HID + u; // xg row for the finalized gate

    // Weights: 4 gate rows of unit u, k in [16kq, 16kq+16) -> 64 VGPRs.
    float w[4][16];
#pragma unroll
    for (int gi = 0; gi < 4; gi++) {
        const float* wr = whh + (size_t)(gi * HID + u) * HID + kq * 16;
#pragma unroll
        for (int k4 = 0; k4 < 4; k4++) {
            float4 t = *(const float4*)(wr + k4 * 4);
            w[gi][k4 * 4 + 0] = t.x; w[gi][k4 * 4 + 1] = t.y;
            w[gi][k4 * 4 + 2] = t.z; w[gi][k4 * 4 + 3] = t.w;
        }
    }

    __shared__ __align__(16) float h_s[2][HID];
    float c_rep = 0.f;            // replicated across the octet
    if (j < HID) h_s[0][j] = first ? 0.f : hst[(size_t)b * HID + j];
    if (!first) c_rep = cst[(size_t)b * HID + u];
    __syncthreads();

    const float mg = (gf == 2) ? 2.f : 1.f;  // tanh(a) = 2/(1+e^-2a)-1

    int buf = 0;
    float xv = xgb[(size_t)(dir ? Tc - 1 : 0) * G4 + row];
    float hlast = 0.f;

    for (int s = 0; s < Tc; s++) {
        const int tt = dir ? (Tc - 1 - s) : s;
        float nxv = 0.f;
        if (s + 1 < Tc) {
            int ttn = dir ? (tt - 1) : (tt + 1);
            nxv = xgb[(size_t)ttn * G4 + row];
        }

        // Partial dot products: 4 gates x 16 k = 64 FMA, 4 ds_read_b128.
        const float* hb = &h_s[buf][kq * 16];
        float p0 = 0.f, p1 = 0.f, p2 = 0.f, p3 = 0.f;
#pragma unroll
        for (int k4 = 0; k4 < 4; k4++) {
            float4 h4 = *(const float4*)(hb + k4 * 4);
            int k = k4 * 4;
            p0 += w[0][k] * h4.x; p1 += w[1][k] * h4.x; p2 += w[2][k] * h4.x; p3 += w[3][k] * h4.x;
            p0 += w[0][k+1] * h4.y; p1 += w[1][k+1] * h4.y; p2 += w[2][k+1] * h4.y; p3 += w[3][k+1] * h4.y;
            p0 += w[0][k+2] * h4.z; p1 += w[1][k+2] * h4.z; p2 += w[2][k+2] * h4.z; p3 += w[3][k+2] * h4.z;
            p0 += w[0][k+3] * h4.w; p1 += w[1][k+3] * h4.w; p2 += w[2][k+3] * h4.w; p3 += w[3][k+3] * h4.w;
        }

        // Butterfly transpose-reduce across the octet (lanes kq=0..7):
        // R1 (xor 4): fold k-chunks kq and kq^4.
        p0 += __shfl_xor(p0, 4, 64);
        p1 += __shfl_xor(p1, 4, 64);
        p2 += __shfl_xor(p2, 4, 64);
        p3 += __shfl_xor(p3, 4, 64);
        // R2 (xor 2): keep gates {kq&2, kq&2+1}, fold partner's k-coverage.
        float s0 = (kq & 2) ? p0 : p2;
        float s1 = (kq & 2) ? p1 : p3;
        float r0 = __shfl_xor(s0, 2, 64);
        float r1 = __shfl_xor(s1, 2, 64);
        float q0 = ((kq & 2) ? p2 : p0) + r0;
        float q1 = ((kq & 2) ? p3 : p1) + r1;
        // R3 (xor 1): keep gate kq&3, full k coverage.
        float s2 = (kq & 1) ? q0 : q1;
        float r2 = __shfl_xor(s2, 1, 64);
        float vv = ((kq & 1) ? q1 : q0) + r2;

        vv += xv;

        // branch-free nonlinearity: sigmoid for gates 0,1,3; tanh for gate 2
        float e = __expf(-mg * vv);
        float gv = mg / (1.f + e) - (mg - 1.f);

        // octet broadcast: gates live on lanes 0..3 of each 8-group
        float vi = __shfl(gv, 0, 8);
        float vf = __shfl(gv, 1, 8);
        float vg = __shfl(gv, 2, 8);
        float vo = __shfl(gv, 3, 8);

        c_rep = vf * c_rep + vi * vg;
        float th = 2.f / (1.f + __expf(-2.f * c_rep)) - 1.f;
        float hv = vo * th;
        hlast = hv;

        if (kq == 0) {
            h_s[buf ^ 1][u] = hv;
            if (MODE == 0)
                hout[((size_t)b * T_SEQ + (tc0 + tt)) * 256 + dir * HID + u] = hv;
        }
        __syncthreads();
        buf ^= 1;
        xv = nxv;
    }

    if (kq == 0) {
        hst[(size_t)b * HID + u] = hlast;
        cst[(size_t)b * HID + u] = c_rep;
    }
}

// ---------------------------------------------------------------------------
// Finale: layer-1 reverse LSTM's t=T-1 output is a SINGLE step from zero
// state (reverse scan processes t=T-1 first), then the FC head.
// ---------------------------------------------------------------------------
__global__ __launch_bounds__(512)
void final_k(const float* __restrict__ h0cat,
             const float* __restrict__ w_ih_r,
             const float* __restrict__ bih_r, const float* __restrict__ bhh_r,
             const float* __restrict__ h1f_last,
             const float* __restrict__ fc_w,
             const float* __restrict__ fc_b,
             float* __restrict__ out)
{
    int b = blockIdx.x;
    int j = threadIdx.x;  // 0..511
    __shared__ __align__(16) float hin[256];
    __shared__ __align__(16) float g_s[G4];
    __shared__ __align__(16) float hcat[256];

    if (j < 256) hin[j] = h0cat[((size_t)b * T_SEQ + (T_SEQ - 1)) * 256 + j];
    __syncthreads();

    float acc = bih_r[j] + bhh_r[j];
    const float* wr = w_ih_r + (size_t)j * 256;
#pragma unroll 8
    for (int k = 0; k < 256; k += 4) {
        float4 h4 = *(const float4*)&hin[k];
        float4 w4 = *(const float4*)&wr[k];
        acc += w4.x * h4.x + w4.y * h4.y + w4.z * h4.z + w4.w * h4.w;
    }
    float v = (j >= 256 && j < 384) ? tanhf_(acc) : sigmoidf_(acc);
    g_s[j] = v;
    if (j < 128) hcat[j] = h1f_last[(size_t)b * HID + j];
    __syncthreads();

    if (j < 128) {
        float gi = g_s[j], gg = g_s[j + 256], go = g_s[j + 384];
        float c = gi * gg;  // f * c0 with c0 = 0
        hcat[128 + j] = go * tanhf_(c);
    }
    __syncthreads();

    if (j < NCLS) {
        float a = fc_b[j];
        const float* fw = fc_w + (size_t)j * 256;
        for (int k = 0; k < 256; k++) a += fw[k] * hcat[k];
        out[(size_t)b * NCLS + j] = a;
    }
}

// ---------------------------------------------------------------------------
// Workspace:
//   [0, 64Mi)            h0cat [B][T][256]                        67,108,864
//   [64Mi, +384Ki)       6 state slots (h,c) x {l0f,l0r,l1f}         393,216
//   [.., +1,835,008)     W splits: W0f1/2, W0r1/2 [512][320] bf16,
//                                  W1f1/2 [512][256] bf16         1,835,008
//   [base, +2*chunk)     xgc0, xgc1 [B][Tc][512] fp32        524,288*Tc
// Tc = largest power of two (<=256) fitting ws_size.
// ---------------------------------------------------------------------------
extern "C" void kernel_launch(void* const* d_in, const int* in_sizes, int n_in,
                              void* d_out, int out_size, void* d_ws, size_t ws_size,
                              hipStream_t stream)
{
    (void)in_sizes; (void)n_in; (void)out_size;

    const int*   x       = (const int*)  d_in[0];
    const float* emb     = (const float*)d_in[1];
    const float* wih_l0f = (const float*)d_in[2];
    const float* whh_l0f = (const float*)d_in[3];
    const float* bih_l0f = (const float*)d_in[4];
    const float* bhh_l0f = (const float*)d_in[5];
    const float* wih_l0r = (const float*)d_in[6];
    const float* whh_l0r = (const float*)d_in[7];
    const float* bih_l0r = (const float*)d_in[8];
    const float* bhh_l0r = (const float*)d_in[9];
    const float* wih_l1f = (const float*)d_in[10];
    const float* whh_l1f = (const float*)d_in[11];
    const float* bih_l1f = (const float*)d_in[12];
    const float* bhh_l1f = (const float*)d_in[13];
    const float* wih_l1r = (const float*)d_in[14];
    const float* whh_l1r = (const float*)d_in[15];  // unused (single step, h0=c0=0)
    const float* bih_l1r = (const float*)d_in[16];
    const float* bhh_l1r = (const float*)d_in[17];
    const float* fc_w    = (const float*)d_in[18];
    const float* fc_b    = (const float*)d_in[19];
    float* out = (float*)d_out;
    (void)whh_l1r;

    char* ws = (char*)d_ws;
    float* h0cat = (float*)ws;
    float* st    = (float*)(ws + (size_t)67108864);
    float* hst0 = st + 0 * 16384;
    float* cst0 = st + 1 * 16384;
    float* hst1 = st + 2 * 16384;
    float* cst1 = st + 3 * 16384;
    float* hst2 = st + 4 * 16384;
    float* cst2 = st + 5 * 16384;

    u16* wsp = (u16*)(ws + (size_t)67108864 + 393216);
    u16* W0f1 = wsp;
    u16* W0f2 = wsp + 163840;
    u16* W0r1 = wsp + 327680;
    u16* W0r2 = wsp + 491520;
    u16* W1f1 = wsp + 655360;
    u16* W1f2 = wsp + 786432;

    const size_t base = (size_t)67108864 + 393216 + 1835008;

    int Tc = 256;
    while (Tc > 32 && base + 2 * (size_t)262144 * Tc > ws_size) Tc >>= 1;
    const int NC = T_SEQ / Tc;
    int tcshift = 0;
    while ((1 << tcshift) < Tc) tcshift++;
    float* xgc0 = (float*)(ws + base);
    float* xgc1 = xgc0 + (size_t)BATCH * Tc * G4;

    const dim3 gemm_grid(Tc * 4);  // (128*Tc/128) M-tiles x 4 N-tiles

    // Weight splits (once per launch)
    prep_w<<<dim3(640), 256, 0, stream>>>(
        wih_l0f, wih_l0r, wih_l1f, W0f1, W0f2, W0r1, W0r2, W1f1, W1f2);

    // Phase 1: layer-0 fwd+rev fused (fwd chunks ascend, rev chunks descend)
    for (int i = 0; i < NC; i++) {
        int cf = i, cr = NC - 1 - i;
        gemm_mfma<<<gemm_grid, 256, 0, stream>>>(
            emb, x, 300, 320, W0f1, W0f2, bih_l0f, bhh_l0f,
            xgc0, tcshift, cf * Tc);
        gemm_mfma<<<gemm_grid, 256, 0, stream>>>(
            emb, x, 300, 320, W0r1, W0r2, bih_l0r, bhh_l0r,
            xgc1, tcshift, cr * Tc);
        lstm_rec<0><<<dim3(2 * BATCH), 1024, 0, stream>>>(
            xgc0, xgc1, whh_l0f, whh_l0r, h0cat,
            hst0, cst0, hst1, cst1, Tc, cf * Tc, cr * Tc, i == 0);
    }

    // Phase 2: layer-1 forward (state only)
    for (int i = 0; i < NC; i++) {
        gemm_mfma<<<gemm_grid, 256, 0, stream>>>(
            h0cat, nullptr, 256, 256, W1f1, W1f2, bih_l1f, bhh_l1f,
            xgc0, tcshift, i * Tc);
        lstm_rec<1><<<dim3(BATCH), 1024, 0, stream>>>(
            xgc0, nullptr, whh_l1f, nullptr, nullptr,
            hst2, cst2, nullptr, nullptr, Tc, i * Tc, 0, i == 0);
    }

    // Phase 3: layer-1 reverse single step + FC head
    final_k<<<dim3(BATCH), 512, 0, stream>>>(
        h0cat, wih_l1r, bih_l1r, bhh_l1r, hst2, fc_w, fc_b, out);
}